// Round 1
// baseline (1256.485 us; speedup 1.0000x reference)
//
#include <hip/hip_runtime.h>
#include <hip/hip_bf16.h>

typedef __attribute__((ext_vector_type(8))) short bf16x8;  // 8 bf16 (4 VGPRs)
typedef __attribute__((ext_vector_type(4))) short bf16x4;
typedef __attribute__((ext_vector_type(4))) float f32x4;   // MFMA C/D frag

__device__ __forceinline__ short f2bs(float v) {
  __hip_bfloat16 h = __float2bfloat16(v);
  return *reinterpret_cast<short*>(&h);
}

// ================ fused weight transforms (one launch) ================
__global__ __launch_bounds__(256) void k_wall(
    const float* __restrict__ rc1w, const float* __restrict__ rc2w,
    const float* __restrict__ d1w, const float* __restrict__ d2w,
    const float* __restrict__ d3w, const float* __restrict__ fcw,
    const float* __restrict__ c1w, const float* __restrict__ pw,
    short* __restrict__ wTr1, short* __restrict__ wTr2, short* __restrict__ wTds1,
    short* __restrict__ wTds2, short* __restrict__ wTds3, short* __restrict__ wfcbf,
    short* __restrict__ wsc, short* __restrict__ wproj) {
  __shared__ float ld[128 * 65];
  const int bx = blockIdx.x;
  const int tid = threadIdx.x;
  if (bx < 4608) {  // res-conv weights: [l][co][ci][3][3] -> [l][tap][co][ci]
    const float* src = (bx < 2304) ? rc1w : rc2w;
    short* dst = (bx < 2304) ? wTr1 : wTr2;
    const int i = (bx % 2304) * 256 + tid;
    if (i < 589824) {
      const int layer = i / 147456;
      const int rem = i % 147456;
      const int tap = rem / 16384;
      const int r2 = rem & 16383;
      const int co = r2 >> 7, ci = r2 & 127;
      dst[i] = f2bs(src[(((size_t)layer * 16384 + co * 128 + ci) * 9) + tap]);
    }
  } else if (bx < 6272) {  // ds weights: [co][ci][4][4] -> [tap][co][ci]
    int CIN, n, base;
    const float* src;
    short* dst;
    if (bx < 4736) { CIN = 32; n = 32768; base = 4608; src = d1w; dst = wTds1; }
    else if (bx < 5248) { CIN = 64; n = 131072; base = 4736; src = d2w; dst = wTds2; }
    else { CIN = 128; n = 262144; base = 5248; src = d3w; dst = wTds3; }
    const int i = (bx - base) * 256 + tid;
    if (i < n) {
      const int COCI = n / 16;
      const int tap = i / COCI;
      const int rem = i % COCI;
      dst[i] = f2bs(src[(size_t)rem * 16 + tap]);
    }
  } else if (bx < 6528) {  // fc: [j][co*64+pix] -> [j][pix*128+co]
    const int j = bx - 6272;
    const float* sp = fcw + (size_t)j * 8192;
    for (int i = tid; i < 8192; i += 256) {
      const int co = i >> 6, pix = i & 63;
      ld[co * 65 + pix] = sp[i];
    }
    __syncthreads();
    short* dp = wfcbf + (size_t)j * 8192;
    for (int i = tid; i < 8192; i += 256) {
      const int pix = i >> 7, co = i & 127;
      dp[i] = f2bs(ld[co * 65 + pix]);
    }
  } else if (bx < 6560) {  // scatter weight: [co][ci] f32 -> bf16
    const int i = (bx - 6528) * 256 + tid;
    if (i < 8192) wsc[i] = f2bs(c1w[i]);
  } else {  // project weight: [co][50] -> [co][64] zero-padded
    const int i = (bx - 6560) * 256 + tid;
    if (i < 2048) {
      const int co = i >> 6, k = i & 63;
      wproj[i] = (k < 50) ? f2bs(pw[co * 50 + k]) : (short)0;
    }
  }
}

// ================ scatter: entity GEMM (MFMA) + relu + scatter-add ================
__global__ __launch_bounds__(256) void k_scatmfma(const float* __restrict__ emb,
                                                  const int* __restrict__ xy,
                                                  const short* __restrict__ wsc,
                                                  float* __restrict__ scat_pm) {
  constexpr int CIP = 264;
  __shared__ short abf[64 * CIP];
  __shared__ int flat[64];
  const int tid = threadIdx.x;
  const int e0 = blockIdx.x * 64;
  const float4* eg = (const float4*)(emb + (size_t)e0 * 256);
  for (int i = tid; i < 4096; i += 256) {
    const int e = i >> 6, k4 = i & 63;
    const float4 v = eg[(size_t)e * 64 + k4];
    bf16x4 o;
    o[0] = f2bs(v.x); o[1] = f2bs(v.y); o[2] = f2bs(v.z); o[3] = f2bs(v.w);
    *(bf16x4*)(&abf[e * CIP + k4 * 4]) = o;
  }
  if (tid < 64) {
    const int* bp = xy + (size_t)(e0 + tid) * 16;
    int xv = 0, yv = 0;
#pragma unroll
    for (int j = 0; j < 8; ++j) xv = (xv << 1) | bp[j];
#pragma unroll
    for (int j = 8; j < 16; ++j) yv = (yv << 1) | bp[j];
    flat[tid] = (bp[0] != -1000000000)
                    ? (((e0 + tid) >> 9) * 4096 + ((yv >> 2) << 6) + (xv >> 2))
                    : -1;
  }
  __syncthreads();
  const int wq = __builtin_amdgcn_readfirstlane(tid >> 6);
  const int lane = tid & 63;
  const int l15 = lane & 15, quad = lane >> 4;
  f32x4 acc[2];
  acc[0] = (f32x4){0.f, 0.f, 0.f, 0.f};
  acc[1] = (f32x4){0.f, 0.f, 0.f, 0.f};
  const short* arow = &abf[(wq * 16 + l15) * CIP + quad * 8];
  const short* w0 = wsc + (size_t)l15 * 256 + quad * 8;
  const short* w1 = wsc + (size_t)(16 + l15) * 256 + quad * 8;
#pragma unroll
  for (int kk = 0; kk < 8; ++kk) {
    bf16x8 a = *(const bf16x8*)(arow + kk * 32);
    acc[0] = __builtin_amdgcn_mfma_f32_16x16x32_bf16(a, *(const bf16x8*)(w0 + kk * 32), acc[0], 0, 0, 0);
    acc[1] = __builtin_amdgcn_mfma_f32_16x16x32_bf16(a, *(const bf16x8*)(w1 + kk * 32), acc[1], 0, 0, 0);
  }
#pragma unroll
  for (int nt = 0; nt < 2; ++nt)
#pragma unroll
    for (int r = 0; r < 4; ++r) {
      const int e = wq * 16 + quad * 4 + r;
      const float v = acc[nt][r];
      const int f = flat[e];
      if (f >= 0 && v > 0.f)
        atomicAdd(&scat_pm[(size_t)f * 32 + nt * 16 + l15], v);
    }
}

// ================ project: concat + 1x1 conv + relu via MFMA -> pm bf16 ================
__global__ __launch_bounds__(256) void k_projmfma(const float* __restrict__ scat_pm,
                                                  const float* __restrict__ xin,
                                                  const short* __restrict__ wproj,
                                                  const float* __restrict__ pb,
                                                  short* __restrict__ h0pm) {
  constexpr int PK = 72;
  __shared__ short abf[128 * PK];
  const int tid = threadIdx.x;
  const int b = blockIdx.x >> 5;
  const int yx0 = (blockIdx.x & 31) << 7;
  const float4* sg = (const float4*)(scat_pm + ((size_t)(b * 4096 + yx0)) * 32);
  for (int i = tid; i < 1024; i += 256) {
    const int p = i >> 3, c4 = i & 7;
    const float4 v = sg[(size_t)p * 8 + c4];
    bf16x4 o;
    o[0] = f2bs(v.x); o[1] = f2bs(v.y); o[2] = f2bs(v.z); o[3] = f2bs(v.w);
    *(bf16x4*)(&abf[p * PK + c4 * 4]) = o;
  }
  for (int i = tid; i < 2304; i += 256) {
    const int run = i >> 7, p = i & 127;
    abf[p * PK + 32 + run] = f2bs(xin[(size_t)(b * 18 + run) * 4096 + yx0 + p]);
  }
  for (int i = tid; i < 2048; i += 256) {
    const int p = i >> 4, k = 50 + (i & 15);
    abf[p * PK + k] = 0;
  }
  __syncthreads();
  const int wq = __builtin_amdgcn_readfirstlane(tid >> 6);
  const int lane = tid & 63;
  const int l15 = lane & 15, quad = lane >> 4;
  f32x4 acc[2][2];
#pragma unroll
  for (int t = 0; t < 2; ++t)
#pragma unroll
    for (int n = 0; n < 2; ++n) acc[t][n] = (f32x4){0.f, 0.f, 0.f, 0.f};
  const short* wb0 = wproj + (size_t)l15 * 64 + quad * 8;
  const short* wb1 = wproj + (size_t)(16 + l15) * 64 + quad * 8;
#pragma unroll
  for (int kk = 0; kk < 2; ++kk) {
    const bf16x8 b0 = *(const bf16x8*)(wb0 + kk * 32);
    const bf16x8 b1 = *(const bf16x8*)(wb1 + kk * 32);
#pragma unroll
    for (int t = 0; t < 2; ++t) {
      const int pix = (wq * 2 + t) * 16 + l15;
      bf16x8 a = *(const bf16x8*)(&abf[pix * PK + quad * 8 + kk * 32]);
      acc[t][0] = __builtin_amdgcn_mfma_f32_16x16x32_bf16(a, b0, acc[t][0], 0, 0, 0);
      acc[t][1] = __builtin_amdgcn_mfma_f32_16x16x32_bf16(a, b1, acc[t][1], 0, 0, 0);
    }
  }
#pragma unroll
  for (int t = 0; t < 2; ++t)
#pragma unroll
    for (int n = 0; n < 2; ++n) {
      const int co = n * 16 + l15;
      const float bv = pb[co];
#pragma unroll
      for (int r = 0; r < 4; ++r) {
        const int pix = (wq * 2 + t) * 16 + quad * 4 + r;
        float v = acc[t][n][r] + bv;
        v = v > 0.f ? v : 0.f;
        h0pm[((size_t)(b * 4096 + yx0 + pix)) * 32 + co] = f2bs(v);
      }
    }
}

// ================ device-scope grid barrier (monotonic counter, no reset) ================
// All 512 blocks co-resident (2/CU: 31.7KB LDS, VGPR<=256 via launch_bounds). Agent-scope
// release (threadfence -> buffer_wbl2) before arrive; relaxed spin; acquire fence
// (threadfence -> buffer_inv) after — cross-XCD safe per the hip CG grid.sync protocol.
__device__ __forceinline__ void gbar(unsigned* cnt, unsigned target) {
  __syncthreads();
  if (threadIdx.x == 0) {
    __threadfence();
    __hip_atomic_fetch_add(cnt, 1u, __ATOMIC_RELEASE, __HIP_MEMORY_SCOPE_AGENT);
    while (__hip_atomic_load(cnt, __ATOMIC_RELAXED, __HIP_MEMORY_SCOPE_AGENT) < target)
      __builtin_amdgcn_s_sleep(1);
    __threadfence();
  }
  __syncthreads();
}

// ---------------- 4x4 s2 p1 conv + bias + relu via MFMA (phase of k_tail) ----------------
template <int CIN, int COUT, int HIN, int ROWSO, int COSPLIT, int MT, int NT, int WRF32>
__device__ __forceinline__ void ds2_phase(int bx, const short* __restrict__ inpm,
                                          const short* __restrict__ wT,
                                          const float* __restrict__ bias,
                                          short* __restrict__ outbf,
                                          float* __restrict__ outf, short* lin) {
  constexpr int HOUT = HIN / 2;
  constexpr int ROWS = 2 * ROWSO + 2;
  constexpr int COLS = HIN + 2;
  constexpr int CHUNKS = CIN / 8;
  constexpr int KK = CIN / 32;
  constexpr int CIPAD = CIN + 8;
  constexpr int NHO = HOUT / ROWSO;
  const int tid = threadIdx.x;
  const int co_blk = (COSPLIT > 1) ? (bx % COSPLIT) : 0;
  if (COSPLIT > 1) bx /= COSPLIT;
  const int hoblk = bx % NHO;
  const int b = bx / NHO;
  __syncthreads();  // guard LDS reuse from previous phase/unit
  for (int i = tid; i < ROWS * COLS * CHUNKS; i += 256) {
    const int ch = i % CHUNKS;
    const int pixv = i / CHUNKS;
    const int r = pixv / COLS, c = pixv % COLS;
    const int hi = 2 * ROWSO * hoblk - 1 + r;
    const int wc = c - 1;
    bf16x8 v = (bf16x8)(short)0;
    if (hi >= 0 && hi < HIN && wc >= 0 && wc < HIN)
      v = *(const bf16x8*)(inpm + ((size_t)(b * HIN + hi) * HIN + wc) * CIN + ch * 8);
    *(bf16x8*)(&lin[(r * COLS + c) * CIPAD + ch * 8]) = v;
  }
  __syncthreads();
  const int wq = __builtin_amdgcn_readfirstlane(tid >> 6);
  const int lane = tid & 63;
  const int l15 = lane & 15, quad = lane >> 4;
  const int mtile = (MT > 1) ? (wq % MT) : 0;
  const int cogrp = wq / MT;
  const int cobase = co_blk * (COUT / COSPLIT) + cogrp * (NT * 16);
  const int p = mtile * 16 + l15;
  const int dr = p / HOUT;
  const int col = p % HOUT;
  f32x4 acc[NT];
#pragma unroll
  for (int n = 0; n < NT; ++n) acc[n] = (f32x4){0.f, 0.f, 0.f, 0.f};
  const short* wrow = wT + (size_t)(cobase + l15) * CIN + quad * 8;
  for (int ky = 0; ky < 4; ++ky) {
    for (int kx = 0; kx < 4; ++kx) {
      const short* arow = &lin[((2 * dr + ky) * COLS + 2 * col + kx) * CIPAD + quad * 8];
      const short* wt = wrow + (size_t)(ky * 4 + kx) * COUT * CIN;
#pragma unroll
      for (int kk = 0; kk < KK; ++kk) {
        bf16x8 a = *(const bf16x8*)(arow + kk * 32);
#pragma unroll
        for (int n = 0; n < NT; ++n) {
          bf16x8 bf = *(const bf16x8*)(wt + n * 16 * CIN + kk * 32);
          acc[n] = __builtin_amdgcn_mfma_f32_16x16x32_bf16(a, bf, acc[n], 0, 0, 0);
        }
      }
    }
  }
#pragma unroll
  for (int n = 0; n < NT; ++n) {
    const int co = cobase + n * 16 + l15;
    const float bv = bias[co];
#pragma unroll
    for (int r = 0; r < 4; ++r) {
      const int pp = mtile * 16 + quad * 4 + r;
      const int dr2 = pp / HOUT;
      const int c2 = pp % HOUT;
      const int ho = hoblk * ROWSO + dr2;
      float v = acc[n][r] + bv;
      v = v > 0.f ? v : 0.f;
      const size_t o = ((size_t)b * HOUT * HOUT + ho * HOUT + c2) * COUT + co;
      outbf[o] = f2bs(v);
      if (WRF32) outf[o] = v;
    }
  }
}

// 3x3 s1 p1 MFMA core on a staged 10x10x128 tile (CIPAD=136)
__device__ __forceinline__ f32x4 res_mfma(const short* lin, const short* __restrict__ wT,
                                          int cobase, int wq, int l15, int quad) {
  const int p = wq * 16 + l15;
  const int py = p >> 3, px = p & 7;
  f32x4 acc = (f32x4){0.f, 0.f, 0.f, 0.f};
  const short* wrow = wT + (size_t)(cobase + l15) * 128 + quad * 8;
  for (int t = 0; t < 9; ++t) {
    const int ky = t / 3, kx = t % 3;
    const short* arow = &lin[((py + ky) * 10 + px + kx) * 136 + quad * 8];
    const short* wt = wrow + (size_t)t * 16384;
#pragma unroll
    for (int kk = 0; kk < 4; ++kk) {
      bf16x8 a = *(const bf16x8*)(arow + kk * 32);
      bf16x8 bf = *(const bf16x8*)(wt + kk * 32);
      acc = __builtin_amdgcn_mfma_f32_16x16x32_bf16(a, bf, acc, 0, 0, 0);
    }
  }
  return acc;
}

// ================ fused tail: ds1+ds2+ds3 + 4 res blocks + map_skip + fc ================
// 512 blocks x 256 threads, persistent, 16 grid barriers. Replaces 18 kernel launches.
__global__ __launch_bounds__(256, 2) void k_tail(
    const short* __restrict__ h0pm,
    const short* __restrict__ wTds1, const float* __restrict__ d1b, short* __restrict__ h1pm,
    const short* __restrict__ wTds2, const float* __restrict__ d2b, short* __restrict__ h2pm,
    const short* __restrict__ wTds3, const float* __restrict__ d3b,
    short* __restrict__ hbf, float* __restrict__ hf32, float* __restrict__ tmppm,
    const short* __restrict__ wTr1, const short* __restrict__ wTr2,
    const float* __restrict__ rbn1g, const float* __restrict__ rbn1b,
    const float* __restrict__ rbn2g, const float* __restrict__ rbn2b,
    float* __restrict__ stats, unsigned* __restrict__ cnt,
    const short* __restrict__ wfc, const float* __restrict__ fcb,
    float* __restrict__ fcpart, float* __restrict__ out0, float* __restrict__ out1) {
  __shared__ short smem[15840];  // max(ds1 6*66*40, ds3 6*18*136, res 100*136 + 256 f32)
  const int bid = blockIdx.x;
  const int tid = threadIdx.x;
  unsigned ph = 0;

  // ---- ds1: [64,64,32]->[32,32,64], 1024 units over 512 blocks ----
  ds2_phase<32, 64, 64, 2, 1, 4, 4, 0>(bid, h0pm, wTds1, d1b, h1pm, nullptr, smem);
  ds2_phase<32, 64, 64, 2, 1, 4, 4, 0>(bid + 512, h0pm, wTds1, d1b, h1pm, nullptr, smem);
  gbar(cnt, 512u * (++ph));
  // ---- ds2: [32,32,64]->[16,16,128] ----
  ds2_phase<64, 128, 32, 1, 1, 1, 2, 0>(bid, h1pm, wTds2, d2b, h2pm, nullptr, smem);
  ds2_phase<64, 128, 32, 1, 1, 1, 2, 0>(bid + 512, h1pm, wTds2, d2b, h2pm, nullptr, smem);
  gbar(cnt, 512u * (++ph));
  // ---- ds3: [16,16,128]->[8,8,128], writes bf16 (conv in) + f32 (identity) ----
  ds2_phase<128, 128, 16, 2, 2, 1, 1, 1>(bid, h2pm, wTds3, d3b, hbf, hf32, smem);
  gbar(cnt, 512u * (++ph));

  // ---- res decomposition: block = (b, 16-cout slice) ----
  const int b = bid >> 3;
  const int cobase = (bid & 7) << 4;
  const int wq = __builtin_amdgcn_readfirstlane(tid >> 6);
  const int lane = tid & 63;
  const int l15 = lane & 15, quad = lane >> 4;
  const int co = cobase + l15;
  float hloc[4], msloc[4];  // identity h and map_skip accum live in registers
  {
    const float* hf = hf32 + ((size_t)b << 13);
#pragma unroll
    for (int r = 0; r < 4; ++r) {
      hloc[r] = hf[(size_t)(wq * 16 + quad * 4 + r) * 128 + co];
      msloc[r] = hloc[r];
    }
  }
  float* const bnsc = (float*)(smem + 13600);
  float* const bnsh = bnsc + 128;

  for (int i = 0; i < 4; ++i) {
    float* sA = stats + i * 512;
    float* sB = sA + 256;
    // -- conv1: stage hbf, MFMA, write raw f32 + stats --
    {
      __syncthreads();
      const short* hb = hbf + ((size_t)b << 13);
      for (int t = tid; t < 1600; t += 256) {
        const int pixel = t >> 4, ch = t & 15;
        const int r = pixel / 10, c = pixel % 10;
        bf16x8 v = (bf16x8)(short)0;
        if (r >= 1 && r <= 8 && c >= 1 && c <= 8)
          v = *(const bf16x8*)(hb + (((r - 1) << 3) + (c - 1)) * 128 + ch * 8);
        *(bf16x8*)(&smem[pixel * 136 + ch * 8]) = v;
      }
      __syncthreads();
      f32x4 acc = res_mfma(smem, wTr1 + (size_t)i * 147456, cobase, wq, l15, quad);
      float* ob = tmppm + ((size_t)b << 13);
      float s = 0.f, q = 0.f;
#pragma unroll
      for (int r = 0; r < 4; ++r) {
        const float v = acc[r];
        ob[(size_t)(wq * 16 + quad * 4 + r) * 128 + co] = v;
        s += v; q += v * v;
      }
      s += __shfl_down(s, 32); q += __shfl_down(q, 32);
      s += __shfl_down(s, 16); q += __shfl_down(q, 16);
      if (lane < 16) {
        atomicAdd(&sA[cobase + lane], s);
        atomicAdd(&sA[128 + cobase + lane], q);
      }
    }
    gbar(cnt, 512u * (++ph));
    // -- conv2: BN1-apply in staging, MFMA, acc stays in regs, stats --
    f32x4 acc2;
    {
      __syncthreads();
      if (tid < 128) {
        const float mu = sA[tid] * (1.f / 4096.f);
        const float var = sA[128 + tid] * (1.f / 4096.f) - mu * mu;
        const float sc = rbn1g[i * 128 + tid] * rsqrtf(var + 1e-5f);
        bnsc[tid] = sc;
        bnsh[tid] = rbn1b[i * 128 + tid] - mu * sc;
      }
      __syncthreads();
      const float* fb = tmppm + ((size_t)b << 13);
      for (int t = tid; t < 3200; t += 256) {
        const int pixel = t >> 5, c4 = t & 31;
        const int r = pixel / 10, c = pixel % 10;
        bf16x4 o = (bf16x4)(short)0;
        if (r >= 1 && r <= 8 && c >= 1 && c <= 8) {
          const float4 x = *(const float4*)(fb + (size_t)(((r - 1) << 3) + (c - 1)) * 128 + c4 * 4);
          const float xv[4] = {x.x, x.y, x.z, x.w};
#pragma unroll
          for (int k2 = 0; k2 < 4; ++k2) {
            const int ci = c4 * 4 + k2;
            const float v = xv[k2] * bnsc[ci] + bnsh[ci];
            o[k2] = f2bs(v > 0.f ? v : 0.f);
          }
        }
        *(bf16x4*)(&smem[pixel * 136 + c4 * 4]) = o;
      }
      __syncthreads();
      acc2 = res_mfma(smem, wTr2 + (size_t)i * 147456, cobase, wq, l15, quad);
      float s = 0.f, q = 0.f;
#pragma unroll
      for (int r = 0; r < 4; ++r) { s += acc2[r]; q += acc2[r] * acc2[r]; }
      s += __shfl_down(s, 32); q += __shfl_down(q, 32);
      s += __shfl_down(s, 16); q += __shfl_down(q, 16);
      if (lane < 16) {
        atomicAdd(&sB[cobase + lane], s);
        atomicAdd(&sB[128 + cobase + lane], q);
      }
    }
    gbar(cnt, 512u * (++ph));
    // -- h-update in registers: BN2 + identity + relu + ms accumulate --
    {
      const float mu = sB[co] * (1.f / 4096.f);
      const float var = sB[128 + co] * (1.f / 4096.f) - mu * mu;
      const float sc = rbn2g[i * 128 + co] * rsqrtf(var + 1e-5f);
      const float sh = rbn2b[i * 128 + co] - mu * sc;
      short* hb = hbf + ((size_t)b << 13);
#pragma unroll
      for (int r = 0; r < 4; ++r) {
        float v = acc2[r] * sc + sh + hloc[r];
        v = v > 0.f ? v : 0.f;
        hloc[r] = v;
        msloc[r] += v;
        hb[(size_t)(wq * 16 + quad * 4 + r) * 128 + co] = f2bs(v);
      }
    }
    gbar(cnt, 512u * (++ph));
  }

  // ---- map_skip: write directly in canonical [b][co][pix] (replaces mstrans) ----
  {
    float* ob = out0 + ((size_t)b << 13) + (size_t)co * 64;
#pragma unroll
    for (int r = 0; r < 4; ++r) ob[wq * 16 + quad * 4 + r] = msloc[r];
  }

  // ---- fc partials: 32 k-chunks x 16 j-tiles over 512 blocks ----
  {
    const int kb = bid >> 4, jb = bid & 15;
    const int k0 = kb * 256 + quad * 8;
    const short* hp = hbf + (size_t)(wq * 16 + l15) * 8192 + k0;
    const short* wp = wfc + (size_t)(jb * 16 + l15) * 8192 + k0;
    f32x4 acc = (f32x4){0.f, 0.f, 0.f, 0.f};
#pragma unroll
    for (int ks = 0; ks < 8; ++ks)
      acc = __builtin_amdgcn_mfma_f32_16x16x32_bf16(*(const bf16x8*)(hp + ks * 32),
                                                    *(const bf16x8*)(wp + ks * 32), acc, 0, 0, 0);
#pragma unroll
    for (int r = 0; r < 4; ++r)
      fcpart[((size_t)kb * 64 + wq * 16 + quad * 4 + r) * 256 + jb * 16 + l15] = acc[r];
  }
  gbar(cnt, 512u * (++ph));
  // ---- fc reduce (blocks 0..63) ----
  if (bid < 64) {
    const int idx = bid * 256 + tid;
    float s = 0.f;
#pragma unroll 8
    for (int kb2 = 0; kb2 < 32; ++kb2) s += fcpart[(size_t)kb2 * 16384 + idx];
    const float v = s + fcb[idx & 255];
    out1[idx] = v > 0.f ? v : 0.f;
  }
}

extern "C" void kernel_launch(void* const* d_in, const int* in_sizes, int n_in,
                              void* d_out, int out_size, void* d_ws, size_t ws_size,
                              hipStream_t stream) {
  const float* xin = (const float*)d_in[0];
  const float* emb = (const float*)d_in[1];
  const int* xy = (const int*)d_in[2];
  const float* c1w = (const float*)d_in[3];
  const float* pw = (const float*)d_in[4];
  const float* pb = (const float*)d_in[5];
  const float* d1w = (const float*)d_in[6];
  const float* d1b = (const float*)d_in[7];
  const float* d2w = (const float*)d_in[8];
  const float* d2b = (const float*)d_in[9];
  const float* d3w = (const float*)d_in[10];
  const float* d3b = (const float*)d_in[11];
  const float* rc1w = (const float*)d_in[12];
  const float* rbn1g = (const float*)d_in[13];
  const float* rbn1b = (const float*)d_in[14];
  const float* rc2w = (const float*)d_in[15];
  const float* rbn2g = (const float*)d_in[16];
  const float* rbn2b = (const float*)d_in[17];
  const float* fcw = (const float*)d_in[18];
  const float* fcb = (const float*)d_in[19];

  float* out0 = (float*)d_out;   // map_skip [64,128,8,8] f32
  float* out1 = out0 + 524288;   // embedded_spatial [64,256] f32

  float* F = (float*)d_ws;
  float* scat = F + 0;                    // [64][4096][32] f32 — dead after projmfma; reused:
  short* h1pm = (short*)(F + 0);          // [64][32][32][64] bf16 (2M shorts)
  short* h2pm = (short*)(F + 2097152);    // [64][16][16][128] bf16 (1M shorts)
  float* hf32 = F + 3145728;              // [64][64][128] f32 (ds3 identity)
  float* tmppm = F + 4194304;             // [64][64][128] f32 (conv1 raw)
  short* hbf = (short*)(F + 5767168);     // [64][64][128] bf16 (h, conv input / fc input)
  float* stats = F + 6291456;             // 4 layers x 512
  unsigned* cnt = (unsigned*)(F + 6293504);  // grid-barrier counter
  float* fcpart = F + 6293568;            // 32 x [64][256] f32, ends 6817856
  short* h0pm = (short*)(F + 8388608);    // [64][4096][32] bf16
  short* wfcbf = (short*)(F + 12582912);
  short* wTr1 = (short*)(F + 13631488);
  short* wTr2 = wTr1 + 589824;
  short* wTds1 = wTr2 + 589824;
  short* wTds2 = wTds1 + 32768;
  short* wTds3 = wTds2 + 131072;
  short* wsc = wTds3 + 262144;            // 8192 shorts
  short* wproj = wsc + 8192;              // 2048 shorts

  hipMemsetAsync(scat, 0, 8388608 * sizeof(float), stream);
  k_wall<<<6568, 256, 0, stream>>>(rc1w, rc2w, d1w, d2w, d3w, fcw, c1w, pw,
                                   wTr1, wTr2, wTds1, wTds2, wTds3, wfcbf, wsc, wproj);
  k_scatmfma<<<512, 256, 0, stream>>>(emb, xy, wsc, scat);
  k_projmfma<<<2048, 256, 0, stream>>>(scat, xin, wproj, pb, h0pm);
  hipMemsetAsync(stats, 0, (2048 + 16) * sizeof(float), stream);  // stats + barrier counter
  k_tail<<<512, 256, 0, stream>>>(h0pm, wTds1, d1b, h1pm, wTds2, d2b, h2pm, wTds3, d3b,
                                  hbf, hf32, tmppm, wTr1, wTr2, rbn1g, rbn1b, rbn2g, rbn2b,
                                  stats, cnt, wfcbf, fcb, fcpart, out0, out1);
}

// Round 2
// 404.425 us; speedup vs baseline: 3.1068x; 3.1068x over previous
//
#include <hip/hip_runtime.h>
#include <hip/hip_bf16.h>

typedef __attribute__((ext_vector_type(8))) short bf16x8;  // 8 bf16 (4 VGPRs)
typedef __attribute__((ext_vector_type(4))) short bf16x4;
typedef __attribute__((ext_vector_type(4))) float f32x4;   // MFMA C/D frag

__device__ __forceinline__ short f2bs(float v) {
  __hip_bfloat16 h = __float2bfloat16(v);
  return *reinterpret_cast<short*>(&h);
}

// ================ fused weight transforms + workspace zeroing (one launch) ================
// [0,4608) res weights | [4608,6272) ds weights | [6272,6528) fc | [6528,6560) scat w
// [6560,6568) proj w | [6568,7080) zero scat 32MB | 7080 zero stats
__global__ __launch_bounds__(256) void k_wall(
    const float* __restrict__ rc1w, const float* __restrict__ rc2w,
    const float* __restrict__ d1w, const float* __restrict__ d2w,
    const float* __restrict__ d3w, const float* __restrict__ fcw,
    const float* __restrict__ c1w, const float* __restrict__ pw,
    short* __restrict__ wTr1, short* __restrict__ wTr2, short* __restrict__ wTds1,
    short* __restrict__ wTds2, short* __restrict__ wTds3, short* __restrict__ wfcbf,
    short* __restrict__ wsc, short* __restrict__ wproj,
    float* __restrict__ scatz, float* __restrict__ statsz) {
  __shared__ float ld[128 * 65];
  const int bx = blockIdx.x;
  const int tid = threadIdx.x;
  if (bx < 4608) {  // res-conv weights: [l][co][ci][3][3] -> [l][tap][co][ci]
    const float* src = (bx < 2304) ? rc1w : rc2w;
    short* dst = (bx < 2304) ? wTr1 : wTr2;
    const int i = (bx % 2304) * 256 + tid;
    if (i < 589824) {
      const int layer = i / 147456;
      const int rem = i % 147456;
      const int tap = rem / 16384;
      const int r2 = rem & 16383;
      const int co = r2 >> 7, ci = r2 & 127;
      dst[i] = f2bs(src[(((size_t)layer * 16384 + co * 128 + ci) * 9) + tap]);
    }
  } else if (bx < 6272) {  // ds weights: [co][ci][4][4] -> [tap][co][ci]
    int CIN, n, base;
    const float* src;
    short* dst;
    if (bx < 4736) { CIN = 32; n = 32768; base = 4608; src = d1w; dst = wTds1; }
    else if (bx < 5248) { CIN = 64; n = 131072; base = 4736; src = d2w; dst = wTds2; }
    else { CIN = 128; n = 262144; base = 5248; src = d3w; dst = wTds3; }
    const int i = (bx - base) * 256 + tid;
    if (i < n) {
      const int COCI = n / 16;
      const int tap = i / COCI;
      const int rem = i % COCI;
      dst[i] = f2bs(src[(size_t)rem * 16 + tap]);
    }
  } else if (bx < 6528) {  // fc: [j][co*64+pix] -> [j][pix*128+co]
    const int j = bx - 6272;
    const float* sp = fcw + (size_t)j * 8192;
    for (int i = tid; i < 8192; i += 256) {
      const int co = i >> 6, pix = i & 63;
      ld[co * 65 + pix] = sp[i];
    }
    __syncthreads();
    short* dp = wfcbf + (size_t)j * 8192;
    for (int i = tid; i < 8192; i += 256) {
      const int pix = i >> 7, co = i & 127;
      dp[i] = f2bs(ld[co * 65 + pix]);
    }
  } else if (bx < 6560) {  // scatter weight: [co][ci] f32 -> bf16
    const int i = (bx - 6528) * 256 + tid;
    if (i < 8192) wsc[i] = f2bs(c1w[i]);
  } else if (bx < 6568) {  // project weight: [co][50] -> [co][64] zero-padded
    const int i = (bx - 6560) * 256 + tid;
    if (i < 2048) {
      const int co = i >> 6, k = i & 63;
      wproj[i] = (k < 50) ? f2bs(pw[co * 50 + k]) : (short)0;
    }
  } else if (bx < 7080) {  // zero scat (8M floats over 512 blocks)
    float4* dst = (float4*)(scatz + (size_t)(bx - 6568) * 16384);
    const float4 z = {0.f, 0.f, 0.f, 0.f};
    for (int t = tid; t < 4096; t += 256) dst[t] = z;
  } else {  // zero stats + pad
    for (int i = tid; i < 2064; i += 256) statsz[i] = 0.f;
  }
}

// ================ scatter: entity GEMM (MFMA) + relu + scatter-add ================
__global__ __launch_bounds__(256) void k_scatmfma(const float* __restrict__ emb,
                                                  const int* __restrict__ xy,
                                                  const short* __restrict__ wsc,
                                                  float* __restrict__ scat_pm) {
  constexpr int CIP = 264;
  __shared__ short abf[64 * CIP];
  __shared__ int flat[64];
  const int tid = threadIdx.x;
  const int e0 = blockIdx.x * 64;
  const float4* eg = (const float4*)(emb + (size_t)e0 * 256);
  for (int i = tid; i < 4096; i += 256) {
    const int e = i >> 6, k4 = i & 63;
    const float4 v = eg[(size_t)e * 64 + k4];
    bf16x4 o;
    o[0] = f2bs(v.x); o[1] = f2bs(v.y); o[2] = f2bs(v.z); o[3] = f2bs(v.w);
    *(bf16x4*)(&abf[e * CIP + k4 * 4]) = o;
  }
  if (tid < 64) {
    const int* bp = xy + (size_t)(e0 + tid) * 16;
    int xv = 0, yv = 0;
#pragma unroll
    for (int j = 0; j < 8; ++j) xv = (xv << 1) | bp[j];
#pragma unroll
    for (int j = 8; j < 16; ++j) yv = (yv << 1) | bp[j];
    flat[tid] = (bp[0] != -1000000000)
                    ? (((e0 + tid) >> 9) * 4096 + ((yv >> 2) << 6) + (xv >> 2))
                    : -1;
  }
  __syncthreads();
  const int wq = __builtin_amdgcn_readfirstlane(tid >> 6);
  const int lane = tid & 63;
  const int l15 = lane & 15, quad = lane >> 4;
  f32x4 acc[2];
  acc[0] = (f32x4){0.f, 0.f, 0.f, 0.f};
  acc[1] = (f32x4){0.f, 0.f, 0.f, 0.f};
  const short* arow = &abf[(wq * 16 + l15) * CIP + quad * 8];
  const short* w0 = wsc + (size_t)l15 * 256 + quad * 8;
  const short* w1 = wsc + (size_t)(16 + l15) * 256 + quad * 8;
#pragma unroll
  for (int kk = 0; kk < 8; ++kk) {
    bf16x8 a = *(const bf16x8*)(arow + kk * 32);
    acc[0] = __builtin_amdgcn_mfma_f32_16x16x32_bf16(a, *(const bf16x8*)(w0 + kk * 32), acc[0], 0, 0, 0);
    acc[1] = __builtin_amdgcn_mfma_f32_16x16x32_bf16(a, *(const bf16x8*)(w1 + kk * 32), acc[1], 0, 0, 0);
  }
#pragma unroll
  for (int nt = 0; nt < 2; ++nt)
#pragma unroll
    for (int r = 0; r < 4; ++r) {
      const int e = wq * 16 + quad * 4 + r;
      const float v = acc[nt][r];
      const int f = flat[e];
      if (f >= 0 && v > 0.f)
        atomicAdd(&scat_pm[(size_t)f * 32 + nt * 16 + l15], v);
    }
}

// ================ project: concat + 1x1 conv + relu via MFMA -> pm bf16 ================
__global__ __launch_bounds__(256) void k_projmfma(const float* __restrict__ scat_pm,
                                                  const float* __restrict__ xin,
                                                  const short* __restrict__ wproj,
                                                  const float* __restrict__ pb,
                                                  short* __restrict__ h0pm) {
  constexpr int PK = 72;
  __shared__ short abf[128 * PK];
  const int tid = threadIdx.x;
  const int b = blockIdx.x >> 5;
  const int yx0 = (blockIdx.x & 31) << 7;
  const float4* sg = (const float4*)(scat_pm + ((size_t)(b * 4096 + yx0)) * 32);
  for (int i = tid; i < 1024; i += 256) {
    const int p = i >> 3, c4 = i & 7;
    const float4 v = sg[(size_t)p * 8 + c4];
    bf16x4 o;
    o[0] = f2bs(v.x); o[1] = f2bs(v.y); o[2] = f2bs(v.z); o[3] = f2bs(v.w);
    *(bf16x4*)(&abf[p * PK + c4 * 4]) = o;
  }
  for (int i = tid; i < 2304; i += 256) {
    const int run = i >> 7, p = i & 127;
    abf[p * PK + 32 + run] = f2bs(xin[(size_t)(b * 18 + run) * 4096 + yx0 + p]);
  }
  for (int i = tid; i < 2048; i += 256) {
    const int p = i >> 4, k = 50 + (i & 15);
    abf[p * PK + k] = 0;
  }
  __syncthreads();
  const int wq = __builtin_amdgcn_readfirstlane(tid >> 6);
  const int lane = tid & 63;
  const int l15 = lane & 15, quad = lane >> 4;
  f32x4 acc[2][2];
#pragma unroll
  for (int t = 0; t < 2; ++t)
#pragma unroll
    for (int n = 0; n < 2; ++n) acc[t][n] = (f32x4){0.f, 0.f, 0.f, 0.f};
  const short* wb0 = wproj + (size_t)l15 * 64 + quad * 8;
  const short* wb1 = wproj + (size_t)(16 + l15) * 64 + quad * 8;
#pragma unroll
  for (int kk = 0; kk < 2; ++kk) {
    const bf16x8 b0 = *(const bf16x8*)(wb0 + kk * 32);
    const bf16x8 b1 = *(const bf16x8*)(wb1 + kk * 32);
#pragma unroll
    for (int t = 0; t < 2; ++t) {
      const int pix = (wq * 2 + t) * 16 + l15;
      bf16x8 a = *(const bf16x8*)(&abf[pix * PK + quad * 8 + kk * 32]);
      acc[t][0] = __builtin_amdgcn_mfma_f32_16x16x32_bf16(a, b0, acc[t][0], 0, 0, 0);
      acc[t][1] = __builtin_amdgcn_mfma_f32_16x16x32_bf16(a, b1, acc[t][1], 0, 0, 0);
    }
  }
#pragma unroll
  for (int t = 0; t < 2; ++t)
#pragma unroll
    for (int n = 0; n < 2; ++n) {
      const int co = n * 16 + l15;
      const float bv = pb[co];
#pragma unroll
      for (int r = 0; r < 4; ++r) {
        const int pix = (wq * 2 + t) * 16 + quad * 4 + r;
        float v = acc[t][n][r] + bv;
        v = v > 0.f ? v : 0.f;
        h0pm[((size_t)(b * 4096 + yx0 + pix)) * 32 + co] = f2bs(v);
      }
    }
}

// ---------------- 4x4 s2 p1 conv + bias + relu via MFMA, pm bf16 in/out ----------------
template <int CIN, int COUT, int HIN, int ROWSO, int COSPLIT, int MT, int NT, int OUTMODE>
__global__ __launch_bounds__(256) void k_ds2(const short* __restrict__ inpm,
                                             const short* __restrict__ wT,
                                             const float* __restrict__ bias,
                                             short* __restrict__ outbf,
                                             float* __restrict__ outf,
                                             float* __restrict__ msf) {
  constexpr int HOUT = HIN / 2;
  constexpr int ROWS = 2 * ROWSO + 2;
  constexpr int COLS = HIN + 2;
  constexpr int CHUNKS = CIN / 8;
  constexpr int KK = CIN / 32;
  constexpr int CIPAD = CIN + 8;
  constexpr int NHO = HOUT / ROWSO;
  __shared__ short lin[ROWS * COLS * CIPAD];
  const int tid = threadIdx.x;
  int bx = blockIdx.x;
  const int co_blk = (COSPLIT > 1) ? (bx % COSPLIT) : 0;
  if (COSPLIT > 1) bx /= COSPLIT;
  const int hoblk = bx % NHO;
  const int b = bx / NHO;
  for (int i = tid; i < ROWS * COLS * CHUNKS; i += 256) {
    const int ch = i % CHUNKS;
    const int pixv = i / CHUNKS;
    const int r = pixv / COLS, c = pixv % COLS;
    const int hi = 2 * ROWSO * hoblk - 1 + r;
    const int wc = c - 1;
    bf16x8 v = (bf16x8)(short)0;
    if (hi >= 0 && hi < HIN && wc >= 0 && wc < HIN)
      v = *(const bf16x8*)(inpm + ((size_t)(b * HIN + hi) * HIN + wc) * CIN + ch * 8);
    *(bf16x8*)(&lin[(r * COLS + c) * CIPAD + ch * 8]) = v;
  }
  __syncthreads();
  const int wq = __builtin_amdgcn_readfirstlane(tid >> 6);
  const int lane = tid & 63;
  const int l15 = lane & 15, quad = lane >> 4;
  const int mtile = (MT > 1) ? (wq % MT) : 0;
  const int cogrp = wq / MT;
  const int cobase = co_blk * (COUT / COSPLIT) + cogrp * (NT * 16);
  const int p = mtile * 16 + l15;
  const int dr = p / HOUT;
  const int col = p % HOUT;
  f32x4 acc[NT];
#pragma unroll
  for (int n = 0; n < NT; ++n) acc[n] = (f32x4){0.f, 0.f, 0.f, 0.f};
  const short* wrow = wT + (size_t)(cobase + l15) * CIN + quad * 8;
  for (int ky = 0; ky < 4; ++ky) {
    for (int kx = 0; kx < 4; ++kx) {
      const short* arow = &lin[((2 * dr + ky) * COLS + 2 * col + kx) * CIPAD + quad * 8];
      const short* wt = wrow + (size_t)(ky * 4 + kx) * COUT * CIN;
#pragma unroll
      for (int kk = 0; kk < KK; ++kk) {
        bf16x8 a = *(const bf16x8*)(arow + kk * 32);
#pragma unroll
        for (int n = 0; n < NT; ++n) {
          bf16x8 bf = *(const bf16x8*)(wt + n * 16 * CIN + kk * 32);
          acc[n] = __builtin_amdgcn_mfma_f32_16x16x32_bf16(a, bf, acc[n], 0, 0, 0);
        }
      }
    }
  }
#pragma unroll
  for (int n = 0; n < NT; ++n) {
    const int co = cobase + n * 16 + l15;
    const float bv = bias[co];
#pragma unroll
    for (int r = 0; r < 4; ++r) {
      const int pp = mtile * 16 + quad * 4 + r;
      const int dr2 = pp / HOUT;
      const int c2 = pp % HOUT;
      const int ho = hoblk * ROWSO + dr2;
      float v = acc[n][r] + bv;
      v = v > 0.f ? v : 0.f;
      const size_t o = ((size_t)b * HOUT * HOUT + ho * HOUT + c2) * COUT + co;
      outbf[o] = f2bs(v);
      if (OUTMODE == 1) {
        outf[o] = v;
        msf[o] = v;
      }
    }
  }
}

// ---------------- 3x3 s1 p1 conv on 8x8 via MFMA, fused stats (res A0 / all B) ----------------
template <int BNIN>
__global__ __launch_bounds__(256) void k_resmfma(const short* __restrict__ hbfin,
                                                 const float* __restrict__ fin,
                                                 const float* __restrict__ statsIn,
                                                 const float* __restrict__ gIn,
                                                 const float* __restrict__ bIn,
                                                 const short* __restrict__ wT,
                                                 float* __restrict__ outpm,
                                                 float* __restrict__ statsOut) {
  constexpr int CIPAD = 136;
  __shared__ short lin[100 * CIPAD];
  __shared__ float bnsc[128], bnsh[128];
  const int tid = threadIdx.x;
  const int b = blockIdx.x >> 3;
  const int cobase = (blockIdx.x & 7) << 4;
  if (BNIN == 1) {
    if (tid < 128) {
      const float mu = statsIn[tid] * (1.f / 4096.f);
      const float var = statsIn[128 + tid] * (1.f / 4096.f) - mu * mu;
      const float sc = gIn[tid] * rsqrtf(var + 1e-5f);
      bnsc[tid] = sc;
      bnsh[tid] = bIn[tid] - mu * sc;
    }
    __syncthreads();
  }
  if (BNIN == 0) {
    const short* hb = hbfin + ((size_t)b << 13);
    for (int i = tid; i < 1600; i += 256) {
      const int pixel = i >> 4, ch = i & 15;
      const int r = pixel / 10, c = pixel % 10;
      bf16x8 v = (bf16x8)(short)0;
      if (r >= 1 && r <= 8 && c >= 1 && c <= 8)
        v = *(const bf16x8*)(hb + (((r - 1) << 3) + (c - 1)) * 128 + ch * 8);
      *(bf16x8*)(&lin[pixel * CIPAD + ch * 8]) = v;
    }
  } else {
    const float* fb = fin + ((size_t)b << 13);
    for (int i = tid; i < 3200; i += 256) {
      const int pixel = i >> 5, c4 = i & 31;
      const int r = pixel / 10, c = pixel % 10;
      bf16x4 o = (bf16x4)(short)0;
      if (r >= 1 && r <= 8 && c >= 1 && c <= 8) {
        const float4 x = *(const float4*)(fb + (size_t)(((r - 1) << 3) + (c - 1)) * 128 + c4 * 4);
        const float xv[4] = {x.x, x.y, x.z, x.w};
#pragma unroll
        for (int k = 0; k < 4; ++k) {
          const int ci = c4 * 4 + k;
          const float v = xv[k] * bnsc[ci] + bnsh[ci];
          o[k] = f2bs(v > 0.f ? v : 0.f);
        }
      }
      *(bf16x4*)(&lin[pixel * CIPAD + c4 * 4]) = o;
    }
  }
  __syncthreads();
  const int wq = __builtin_amdgcn_readfirstlane(tid >> 6);
  const int lane = tid & 63;
  const int l15 = lane & 15, quad = lane >> 4;
  const int p = wq * 16 + l15;
  const int py = p >> 3, px = p & 7;
  f32x4 acc = (f32x4){0.f, 0.f, 0.f, 0.f};
  const short* wrow = wT + (size_t)(cobase + l15) * 128 + quad * 8;
  for (int t = 0; t < 9; ++t) {
    const int ky = t / 3, kx = t % 3;
    const short* arow = &lin[((py + ky) * 10 + px + kx) * CIPAD + quad * 8];
    const short* wt = wrow + (size_t)t * 16384;
#pragma unroll
    for (int kk = 0; kk < 4; ++kk) {
      bf16x8 a = *(const bf16x8*)(arow + kk * 32);
      bf16x8 bf = *(const bf16x8*)(wt + kk * 32);
      acc = __builtin_amdgcn_mfma_f32_16x16x32_bf16(a, bf, acc, 0, 0, 0);
    }
  }
  float* ob = outpm + ((size_t)b << 13);
  const int co = cobase + l15;
  float s = 0.f, q = 0.f;
#pragma unroll
  for (int r = 0; r < 4; ++r) {
    const float v = acc[r];
    ob[(size_t)(wq * 16 + quad * 4 + r) * 128 + co] = v;
    s += v;
    q += v * v;
  }
  s += __shfl_down(s, 32); q += __shfl_down(q, 32);
  s += __shfl_down(s, 16); q += __shfl_down(q, 16);
  if (lane < 16) {
    atomicAdd(&statsOut[co], s);
    atomicAdd(&statsOut[128 + co], q);
  }
}

// ---------------- conv1 of res-iter i>=1: BN2(prev)+identity+relu fused into staging ----------------
// Replaces k_bnadd: each (b, co-slice) block also writes its 16-ch slice of h_i (f32) and ms +=.
__global__ __launch_bounds__(256) void k_resA(const float* __restrict__ tmp2,   // conv2 raw (prev)
                                              const float* __restrict__ statsB,
                                              const float* __restrict__ g2,
                                              const float* __restrict__ b2,
                                              const float* __restrict__ identf, // h_{i-1} f32
                                              float* __restrict__ houtf,       // h_i f32 (slice)
                                              float* __restrict__ mspm,        // ms accum (slice)
                                              const short* __restrict__ wT,
                                              float* __restrict__ outpm,       // conv1 raw
                                              float* __restrict__ statsOut) {
  constexpr int CIPAD = 136;
  __shared__ short lin[100 * CIPAD];
  __shared__ float bnsc[128], bnsh[128];
  const int tid = threadIdx.x;
  const int b = blockIdx.x >> 3;
  const int cobase = (blockIdx.x & 7) << 4;
  if (tid < 128) {
    const float mu = statsB[tid] * (1.f / 4096.f);
    const float var = statsB[128 + tid] * (1.f / 4096.f) - mu * mu;
    const float sc = g2[tid] * rsqrtf(var + 1e-5f);
    bnsc[tid] = sc;
    bnsh[tid] = b2[tid] - mu * sc;
  }
  __syncthreads();
  const float* fb = tmp2 + ((size_t)b << 13);
  const float* idb = identf + ((size_t)b << 13);
  // stage h_i = relu(BN2(tmp2) + ident) for all 128 ch into LDS bf16 (10x10 padded)
  for (int t = tid; t < 3200; t += 256) {
    const int pixel = t >> 5, c4 = t & 31;
    const int r = pixel / 10, c = pixel % 10;
    bf16x4 o = (bf16x4)(short)0;
    if (r >= 1 && r <= 8 && c >= 1 && c <= 8) {
      const size_t p8 = (size_t)(((r - 1) << 3) + (c - 1)) * 128 + c4 * 4;
      const float4 x = *(const float4*)(fb + p8);
      const float4 id = *(const float4*)(idb + p8);
      const float xv[4] = {x.x, x.y, x.z, x.w};
      const float iv[4] = {id.x, id.y, id.z, id.w};
#pragma unroll
      for (int k = 0; k < 4; ++k) {
        const int ci = c4 * 4 + k;
        const float v = xv[k] * bnsc[ci] + bnsh[ci] + iv[k];
        o[k] = f2bs(v > 0.f ? v : 0.f);
      }
    }
    *(bf16x4*)(&lin[pixel * CIPAD + c4 * 4]) = o;
  }
  // slice h/ms writes: 64 pix x 16 ch, each element owned by exactly one block
  for (int t = tid; t < 1024; t += 256) {
    const int pix = t >> 4, cl = t & 15;
    const int cow = cobase + cl;
    const size_t o = ((size_t)b << 13) + (size_t)pix * 128 + cow;
    float v = tmp2[o] * bnsc[cow] + bnsh[cow] + identf[o];
    v = v > 0.f ? v : 0.f;
    houtf[o] = v;
    mspm[o] += v;
  }
  __syncthreads();
  const int wq = __builtin_amdgcn_readfirstlane(tid >> 6);
  const int lane = tid & 63;
  const int l15 = lane & 15, quad = lane >> 4;
  const int p = wq * 16 + l15;
  const int py = p >> 3, px = p & 7;
  f32x4 acc = (f32x4){0.f, 0.f, 0.f, 0.f};
  const short* wrow = wT + (size_t)(cobase + l15) * 128 + quad * 8;
  for (int t = 0; t < 9; ++t) {
    const int ky = t / 3, kx = t % 3;
    const short* arow = &lin[((py + ky) * 10 + px + kx) * CIPAD + quad * 8];
    const short* wt = wrow + (size_t)t * 16384;
#pragma unroll
    for (int kk = 0; kk < 4; ++kk) {
      bf16x8 a = *(const bf16x8*)(arow + kk * 32);
      bf16x8 bf = *(const bf16x8*)(wt + kk * 32);
      acc = __builtin_amdgcn_mfma_f32_16x16x32_bf16(a, bf, acc, 0, 0, 0);
    }
  }
  float* ob = outpm + ((size_t)b << 13);
  const int co = cobase + l15;
  float s = 0.f, q = 0.f;
#pragma unroll
  for (int r = 0; r < 4; ++r) {
    const float v = acc[r];
    ob[(size_t)(wq * 16 + quad * 4 + r) * 128 + co] = v;
    s += v;
    q += v * v;
  }
  s += __shfl_down(s, 32); q += __shfl_down(q, 32);
  s += __shfl_down(s, 16); q += __shfl_down(q, 16);
  if (lane < 16) {
    atomicAdd(&statsOut[co], s);
    atomicAdd(&statsOut[128 + co], q);
  }
}

// ---------------- epilogue: h4 = BN2+ident+relu; hbf (fc input) + map_skip -> out0 ----------------
__global__ __launch_bounds__(256) void k_msfin(const float* __restrict__ tmp2,
                                               const float* __restrict__ statsB,
                                               const float* __restrict__ g2,
                                               const float* __restrict__ b2,
                                               const float* __restrict__ identf,
                                               const float* __restrict__ mspm,
                                               short* __restrict__ hbf,
                                               float* __restrict__ out0) {
  __shared__ float t[64 * 132];
  __shared__ float bnsc[128], bnsh[128];
  const int b = blockIdx.x;
  const int tid = threadIdx.x;
  if (tid < 128) {
    const float mu = statsB[tid] * (1.f / 4096.f);
    const float var = statsB[128 + tid] * (1.f / 4096.f) - mu * mu;
    const float sc = g2[tid] * rsqrtf(var + 1e-5f);
    bnsc[tid] = sc;
    bnsh[tid] = b2[tid] - mu * sc;
  }
  __syncthreads();
  const size_t base = (size_t)b << 13;
  for (int i = tid; i < 8192; i += 256) {
    const int pix = i >> 7, co = i & 127;
    float v = tmp2[base + i] * bnsc[co] + bnsh[co] + identf[base + i];
    v = v > 0.f ? v : 0.f;
    hbf[base + i] = f2bs(v);
    t[pix * 132 + co] = mspm[base + i] + v;
  }
  __syncthreads();
  for (int i = tid; i < 8192; i += 256) {
    const int co = i >> 6, pix = i & 63;
    out0[base + i] = t[pix * 132 + co];
  }
}

// ---------------- FC via MFMA: k-split partials ----------------
__global__ __launch_bounds__(256) void k_fcmfma(const short* __restrict__ hbf,
                                                const short* __restrict__ wbf,
                                                float* __restrict__ part) {
  const int nb = blockIdx.x & 3;
  const int kb = blockIdx.x >> 2;
  const int wq = __builtin_amdgcn_readfirstlane((int)(threadIdx.x >> 6));
  const int lane = threadIdx.x & 63;
  const int l15 = lane & 15, quad = lane >> 4;
  const int k0 = kb * 256 + quad * 8;
  const short* wp = wbf + (size_t)(nb * 64 + wq * 16 + l15) * 8192 + k0;
  const short* hp = hbf + (size_t)l15 * 8192 + k0;
  f32x4 acc[4];
#pragma unroll
  for (int m = 0; m < 4; ++m) acc[m] = (f32x4){0.f, 0.f, 0.f, 0.f};
  for (int ks = 0; ks < 8; ++ks) {
    bf16x8 bfr = *(const bf16x8*)(wp + ks * 32);
#pragma unroll
    for (int m = 0; m < 4; ++m) {
      bf16x8 a = *(const bf16x8*)(hp + (size_t)m * 16 * 8192 + ks * 32);
      acc[m] = __builtin_amdgcn_mfma_f32_16x16x32_bf16(a, bfr, acc[m], 0, 0, 0);
    }
  }
#pragma unroll
  for (int m = 0; m < 4; ++m)
#pragma unroll
    for (int r = 0; r < 4; ++r) {
      const int b = m * 16 + quad * 4 + r;
      part[((size_t)kb * 64 + b) * 256 + nb * 64 + wq * 16 + l15] = acc[m][r];
    }
}

__global__ __launch_bounds__(256) void k_fcred(const float* __restrict__ part,
                                               const float* __restrict__ bias,
                                               float* __restrict__ out1) {
  const int idx = blockIdx.x * 256 + threadIdx.x;
  const int j = idx & 255;
  float s = 0.f;
#pragma unroll 8
  for (int kb = 0; kb < 32; ++kb) s += part[(size_t)kb * 16384 + idx];
  const float v = s + bias[j];
  out1[idx] = v > 0.f ? v : 0.f;
}

extern "C" void kernel_launch(void* const* d_in, const int* in_sizes, int n_in,
                              void* d_out, int out_size, void* d_ws, size_t ws_size,
                              hipStream_t stream) {
  const float* xin = (const float*)d_in[0];
  const float* emb = (const float*)d_in[1];
  const int* xy = (const int*)d_in[2];
  const float* c1w = (const float*)d_in[3];
  const float* pw = (const float*)d_in[4];
  const float* pb = (const float*)d_in[5];
  const float* d1w = (const float*)d_in[6];
  const float* d1b = (const float*)d_in[7];
  const float* d2w = (const float*)d_in[8];
  const float* d2b = (const float*)d_in[9];
  const float* d3w = (const float*)d_in[10];
  const float* d3b = (const float*)d_in[11];
  const float* rc1w = (const float*)d_in[12];
  const float* rbn1g = (const float*)d_in[13];
  const float* rbn1b = (const float*)d_in[14];
  const float* rc2w = (const float*)d_in[15];
  const float* rbn2g = (const float*)d_in[16];
  const float* rbn2b = (const float*)d_in[17];
  const float* fcw = (const float*)d_in[18];
  const float* fcb = (const float*)d_in[19];

  float* out0 = (float*)d_out;   // map_skip [64,128,8,8] f32
  float* out1 = out0 + 524288;   // embedded_spatial [64,256] f32

  float* F = (float*)d_ws;
  float* scat = F + 0;                    // [64][4096][32] f32 — dead after projmfma; reused:
  short* h1pm = (short*)(F + 0);          // [64][32][32][64] bf16
  short* h2pm = (short*)(F + 2097152);    // [64][16][16][128] bf16
  float* hApm = F + 3145728;              // h ping (f32, identity chain)
  float* hBpm = F + 3670016;              // h pong
  float* tmppm = F + 4194304;             // conv1 raw f32
  float* tmp2pm = F + 4718592;            // conv2 raw f32
  float* mspm = F + 5242880;              // map_skip accum (pm)
  short* pmbfA = (short*)(F + 5767168);   // h0 bf16 (conv input, iter 0)
  short* hbf = (short*)(F + 6029312);     // final h bf16 (fc input)
  float* stats = F + 6291456;             // 4 layers x 512 (+pad)
  float* fcpart = F + 6293504;            // 32 x [64][256] f32, ends 6817792 < 8388608
  short* h0pm = (short*)(F + 8388608);    // [64][4096][32] bf16
  short* wfcbf = (short*)(F + 12582912);
  short* wTr1 = (short*)(F + 13631488);
  short* wTr2 = wTr1 + 589824;
  short* wTds1 = wTr2 + 589824;
  short* wTds2 = wTds1 + 32768;
  short* wTds3 = wTds2 + 131072;
  short* wsc = wTds3 + 262144;            // 8192 shorts
  short* wproj = wsc + 8192;              // 2048 shorts

  k_wall<<<7081, 256, 0, stream>>>(rc1w, rc2w, d1w, d2w, d3w, fcw, c1w, pw,
                                   wTr1, wTr2, wTds1, wTds2, wTds3, wfcbf, wsc, wproj,
                                   scat, stats);
  k_scatmfma<<<512, 256, 0, stream>>>(emb, xy, wsc, scat);
  k_projmfma<<<2048, 256, 0, stream>>>(scat, xin, wproj, pb, h0pm);
  k_ds2<32, 64, 64, 2, 1, 4, 4, 0><<<1024, 256, 0, stream>>>(h0pm, wTds1, d1b, h1pm, nullptr, nullptr);
  k_ds2<64, 128, 32, 1, 1, 1, 2, 0><<<1024, 256, 0, stream>>>(h1pm, wTds2, d2b, h2pm, nullptr, nullptr);
  // ds3 writes h0 bf16 (conv in), h0 f32 (identity), ms init
  k_ds2<128, 128, 16, 2, 2, 1, 1, 1><<<512, 256, 0, stream>>>(h2pm, wTds3, d3b, pmbfA, hApm, mspm);

  // iter 0
  k_resmfma<0><<<512, 256, 0, stream>>>(pmbfA, nullptr, nullptr, nullptr, nullptr,
                                        wTr1, tmppm, stats);
  k_resmfma<1><<<512, 256, 0, stream>>>(nullptr, tmppm, stats, rbn1g, rbn1b,
                                        wTr2, tmp2pm, stats + 256);
  // iters 1..3: conv1 fused with BN2(prev)+identity+relu (+h/ms slice writes)
  float* idp = hApm;  // h_{i-1}
  float* hop = hBpm;  // h_i
  for (int i = 1; i < 4; ++i) {
    k_resA<<<512, 256, 0, stream>>>(tmp2pm, stats + (i - 1) * 512 + 256,
                                    rbn2g + (i - 1) * 128, rbn2b + (i - 1) * 128,
                                    idp, hop, mspm, wTr1 + (size_t)i * 147456,
                                    tmppm, stats + i * 512);
    k_resmfma<1><<<512, 256, 0, stream>>>(nullptr, tmppm, stats + i * 512,
                                          rbn1g + i * 128, rbn1b + i * 128,
                                          wTr2 + (size_t)i * 147456, tmp2pm,
                                          stats + i * 512 + 256);
    float* sw = idp; idp = hop; hop = sw;
  }
  // epilogue: h4, fc input, map_skip -> out0  (idp now holds h_3)
  k_msfin<<<64, 256, 0, stream>>>(tmp2pm, stats + 3 * 512 + 256, rbn2g + 3 * 128,
                                  rbn2b + 3 * 128, idp, mspm, hbf, out0);
  k_fcmfma<<<128, 256, 0, stream>>>(hbf, wfcbf, fcpart);
  k_fcred<<<64, 256, 0, stream>>>(fcpart, fcb, out1);
}